// Round 15
// baseline (161.115 us; speedup 1.0000x reference)
//
#include <hip/hip_runtime.h>

// Problem constants
#define N_ROWS 131072    // 32*4096
#define D 64
#define K_CODES 1024

typedef _Float16 f16x8 __attribute__((ext_vector_type(8)));
typedef float    f32x4 __attribute__((ext_vector_type(4)));

#define MFMA16(a, b, c) __builtin_amdgcn_mfma_f32_16x16x32_f16((a), (b), (c), 0, 0, 0)

// ---------------------------------------------------------------------------
// ws layout: csqr[1024] f32 (4 KB) | CBf: 16384 f16x8 units (256 KB)
// 16x16x32 fragment order. CBf unit index = tile*256 + f*64 + lane,
// f in {0:hi k0-31, 1:hi k32-63, 2:lo k0-31, 3:lo k32-63}; unit holds the
// 8 halves lane needs for that MFMA B fragment:
// B[k=(lane>>4)*8+j][n=lane&15], code = tile*16 + n.
// CBf stores the hi/lo split of (-2*c); dist = |c|^2 + x.(-2c).
// (Correctness-verified rounds 2-14.)
// ---------------------------------------------------------------------------
__global__ __launch_bounds__(256)
void prep_kernel(const float* __restrict__ CB, _Float16* __restrict__ CBf,
                 float* __restrict__ csqr, float* __restrict__ loss) {
    const int b = blockIdx.x, t = threadIdx.x;
    if (b < 64) {
        const int unit = b * 256 + t;
        const int tile = unit >> 8;
        const int f    = (unit >> 6) & 3;
        const int lane = unit & 63;
        const int quad = lane >> 4, lrow = lane & 15;
        const int code = tile * 16 + lrow;
        const int k0   = (f & 1) * 32 + quad * 8;
        const float* src = CB + (size_t)code * D + k0;
        float4 v0 = *(const float4*)(src);
        float4 v1 = *(const float4*)(src + 4);
        float xs[8] = {v0.x, v0.y, v0.z, v0.w, v1.x, v1.y, v1.z, v1.w};
        f16x8 o;
#pragma unroll
        for (int j = 0; j < 8; ++j) {
            float sv = -2.0f * xs[j];
            _Float16 h = (_Float16)sv;
            o[j] = (f < 2) ? h : (_Float16)(sv - (float)h);
        }
        *(f16x8*)(CBf + (size_t)unit * 8) = o;
    } else {
        if (t == 0) *loss = 0.0f;
        for (int k = t; k < K_CODES; k += 256) {
            const float4* p = (const float4*)(CB + (size_t)k * D);
            float s = 0.0f;
#pragma unroll
            for (int i = 0; i < 16; ++i) {
                float4 v = p[i];
                s += v.x * v.x + v.y * v.y + v.z * v.z + v.w * v.w;
            }
            csqr[k] = s;
        }
    }
}

// ---------------------------------------------------------------------------
// Direct global->LDS 16B copy (lane-linear dest: wave-uniform base + lane*16).
// ---------------------------------------------------------------------------
__device__ __forceinline__ void gload_lds16(const void* g, void* l) {
    __builtin_amdgcn_global_load_lds(
        (const __attribute__((address_space(1))) void*)g,
        (__attribute__((address_space(3))) void*)l,
        16, 0, 0);
}

// ---------------------------------------------------------------------------
// K1 (wave phase-stagger): R10 base (measured 64.9us), ONE change. Theory:
// the full falsification matrix (ILP R4, barriers R5/R10, grain R6,
// occupancy R7-R9, manual pipeline R12, fusion R13, compiler pipeline R14)
// leaves exactly one account of the 33%-on-all-pipes plateau — runtime
// 153k cyc = 4 waves/SIMD x 64 tiles x ~600-cyc chain with ZERO cross-wave
// overlap: waves restart each pass from the same barrier with the same
// instruction stream and CONVOY (everyone's ds_read burst together, then
// everyone's MFMA cluster together; pipes alternate idle). Fix: wave w
// consumes the pass's 16 tiles in rotated order (i + 2w) & 15 — 8 waves
// pinned to 8 distinct phases, guaranteed mixed pipe demand at any
// instant. Correctness: in-lane argmin no longer sees ascending code
// order -> full lexicographic (dist, idx) compare per slot (order-
// independent, exactly np.argmin first-min; distances per (row,code) are
// bit-deterministic so equality is well-defined); the 16-lane column
// reduce was already lexicographic. Everything else verbatim R10:
// 512 thr = 8 waves x 32 rows (MT=2), grid 512 = 2 blocks/CU, 4 passes x
// 16 tiles, single 64 KB buffer, 8 gload_lds/thread stage, free-run
// consume, 8 barriers total, (512,4) 64-reg point, split numerics
// (hh,hh,lh,lh,hl,hl; ll dropped), acc-init=csqr, 256-row zq epilogue.
// ---------------------------------------------------------------------------
__global__ __launch_bounds__(512, 4)
void argmin_kernel(const float* __restrict__ X,
                   const _Float16* __restrict__ CBf,
                   const float* __restrict__ csqr,
                   const float* __restrict__ CB,
                   float* __restrict__ out) {
    __shared__ _Float16 Bbuf[16][2048];   // 64 KB: 16 tiles x 4 KB (one pass)
    __shared__ float LsC[K_CODES];        // csqr copy, 4 KB
    __shared__ int   ivfin[256];
    __shared__ float lsum[8];

    const int t    = threadIdx.x;         // 0..511
    const int wave = t >> 6;              // 0..7
    const int lane = t & 63;
    const int quad = lane >> 4;
    const int lrow = lane & 15;
    const int R0   = blockIdx.x * 256;
    const int Rw   = R0 + wave * 32;      // this wave's 32 rows

// Stage pass p (16 tiles = 4096 units of 16B): 512 threads x 8 gload_lds.
#define STAGE(p_)                                                             \
    do {                                                                      \
        _Pragma("unroll")                                                     \
        for (int i_ = 0; i_ < 8; ++i_) {                                      \
            const int u_ = i_ * 512 + t;                                      \
            const f16x8* gp_ =                                                \
                (const f16x8*)CBf + (size_t)((p_) * 4096 + u_);               \
            gload_lds16((const void*)gp_,                                     \
                        (void*)((char*)&Bbuf[0][0] + (size_t)u_ * 16));       \
        }                                                                     \
    } while (0)

    STAGE(0);                          // pass-0 B in flight ASAP

    // csqr -> LDS (covered by the prologue __syncthreads).
    if (t < 256) ((float4*)LsC)[t] = ((const float4*)csqr)[t];

    // ---- A fragments (MT=2): split(x) hi/lo. Lane holds
    // A[m=lrow][k=quad*8+j] for rows Rw+mt*16+lrow; quads x ks cover the 64
    // columns -> per-wave xsq counts each of its 32x64 elements once.
    f16x8 Ah[2][2], Al[2][2];
    float xsq = 0.0f;
#pragma unroll
    for (int mt = 0; mt < 2; ++mt) {
        const float* xr = X + (size_t)(Rw + mt * 16 + lrow) * D;
#pragma unroll
        for (int ks = 0; ks < 2; ++ks) {
            const int k0 = ks * 32 + quad * 8;
            float4 v0 = *(const float4*)(xr + k0);
            float4 v1 = *(const float4*)(xr + k0 + 4);
            float xs[8] = {v0.x, v0.y, v0.z, v0.w, v1.x, v1.y, v1.z, v1.w};
            f16x8 h, l;
#pragma unroll
            for (int j = 0; j < 8; ++j) {
                xsq += xs[j] * xs[j];
                _Float16 hh = (_Float16)xs[j];
                h[j] = hh;
                l[j] = (_Float16)(xs[j] - (float)hh);
            }
            Ah[mt][ks] = h;
            Al[mt][ks] = l;
        }
    }

    float bestd[2][4];
    int   besti[2][4];
#pragma unroll
    for (int mt = 0; mt < 2; ++mt)
#pragma unroll
        for (int r = 0; r < 4; ++r) { bestd[mt][r] = 3.0e38f; besti[mt][r] = 0; }

    __syncthreads();   // pass-0 B + LsC + A ready (full drain, prologue)

    // ---- 4 passes x 16 tiles, per-wave rotated tile order (phase stagger).
    for (int p = 0; p < 4; ++p) {
        if (p) {
            __syncthreads();           // all waves done reading pass p-1
            STAGE(p);
            asm volatile("s_waitcnt vmcnt(0)" ::: "memory");
            __syncthreads();           // pass-p B visible to all waves
        }
#pragma unroll 4
        for (int i = 0; i < 16; ++i) {
            const int it = (i + wave * 2) & 15;    // wave-unique phase
            const f16x8* Bt = (const f16x8*)&Bbuf[it][0] + lane;
            f16x8 b0 = Bt[0], b1 = Bt[64], b2 = Bt[128], b3 = Bt[192];
            const int   c  = (p * 16 + it) * 16 + lrow;
            const float cs = LsC[c];
#pragma unroll
            for (int mt = 0; mt < 2; ++mt) {
                f32x4 acc = {cs, cs, cs, cs};
                acc = MFMA16(Ah[mt][0], b0, acc);
                acc = MFMA16(Ah[mt][1], b1, acc);
                acc = MFMA16(Al[mt][0], b0, acc);
                acc = MFMA16(Al[mt][1], b1, acc);
                acc = MFMA16(Ah[mt][0], b2, acc);
                acc = MFMA16(Ah[mt][1], b3, acc);
#pragma unroll
                for (int r = 0; r < 4; ++r) {
                    // Lexicographic (dist, idx): order-independent first-min.
                    bool lt = (acc[r] < bestd[mt][r]) ||
                              (acc[r] == bestd[mt][r] && c < besti[mt][r]);
                    bestd[mt][r] = lt ? acc[r] : bestd[mt][r];
                    besti[mt][r] = lt ? c : besti[mt][r];
                }
            }
        }
    }

    // ---- Finalize: 16-lane column reduce (lexicographic on exact ties);
    // lrow==0 lanes hold rows Rw + mt*16 + quad*4 + r (C layout:
    // row = quad*4 + r, col = lrow — verified rounds 0-14).
    float dvsum = 0.0f;
#pragma unroll
    for (int mt = 0; mt < 2; ++mt) {
#pragma unroll
        for (int r = 0; r < 4; ++r) {
            float dv = bestd[mt][r];
            int   iv = besti[mt][r];
#pragma unroll
            for (int m = 1; m < 16; m <<= 1) {
                float od = __shfl_xor(dv, m, 64);
                int   oi = __shfl_xor(iv, m, 64);
                if (od < dv || (od == dv && oi < iv)) { dv = od; iv = oi; }
            }
            if (lrow == 0) {
                const int rl = wave * 32 + mt * 16 + quad * 4 + r;  // 0..255
                ivfin[rl] = iv;
                out[1 + (size_t)N_ROWS * D + R0 + rl] = (float)iv;  // idxf
                dvsum += dv;
            }
        }
    }

    // ---- Loss partial: xsq (all lanes) + dvsum (lrow==0 lanes) reduce.
    {
        float s = xsq + dvsum;
#pragma unroll
        for (int m = 1; m < 64; m <<= 1) s += __shfl_xor(s, m, 64);
        if (lane == 0) lsum[wave] = s;
    }
    __syncthreads();                             // ivfin + lsum ready

    const float scale = 1.25f / (float)((size_t)N_ROWS * D);
    if (t == 0) {
        float L = 0.0f;
#pragma unroll
        for (int w = 0; w < 8; ++w) L += lsum[w];
        atomicAdd(out, L * scale);
    }

    // ---- Block-cooperative zq span write: dwords [R0*64, R0*64+16384) at
    // out+1. Global dword offset 1+R0*64+j is 16B-aligned iff j%4==3.
    float* p = out + 1 + (size_t)R0 * D;
#pragma unroll
    for (int i = 0; i < 8; ++i) {
        int q = i * 512 + t;        // 0..4095
        int j = 4 * q + 3;          // 3,7,...,16383
        if (q < 4095) {
            float v[4];
#pragma unroll
            for (int e = 0; e < 4; ++e) {
                int jj = j + e;     // may straddle a row boundary
                v[e] = CB[(size_t)ivfin[jj >> 6] * D + (jj & 63)];
            }
            *(float4*)(p + j) = make_float4(v[0], v[1], v[2], v[3]);
        } else if (q == 4095) {
            p[16383] = CB[(size_t)ivfin[255] * D + 63];
        }
    }
    if (t == 0) {   // head dwords j=0..2 (row 0, cols 0..2)
        const float* c0 = CB + (size_t)ivfin[0] * D;
        p[0] = c0[0];
        p[1] = c0[1];
        p[2] = c0[2];
    }
}

// ---------------------------------------------------------------------------
extern "C" void kernel_launch(void* const* d_in, const int* in_sizes, int n_in,
                              void* d_out, int out_size, void* d_ws,
                              size_t ws_size, hipStream_t stream) {
    const float* X  = (const float*)d_in[0];   // inputs  [131072,64]
    const float* CB = (const float*)d_in[1];   // codebook [1024,64]

    float*    csqr = (float*)d_ws;                      // 4 KB
    _Float16* CBf  = (_Float16*)((char*)d_ws + 4096);   // 256 KB

    hipLaunchKernelGGL(prep_kernel, dim3(65), dim3(256), 0, stream,
                       CB, CBf, csqr, (float*)d_out);
    hipLaunchKernelGGL(argmin_kernel, dim3(N_ROWS / 256), dim3(512), 0, stream,
                       X, CBf, csqr, CB, (float*)d_out);
}

// Round 16
// 143.480 us; speedup vs baseline: 1.1229x; 1.1229x over previous
//
#include <hip/hip_runtime.h>

// Problem constants
#define N_ROWS 131072    // 32*4096
#define D 64
#define K_CODES 1024

typedef _Float16 f16x8 __attribute__((ext_vector_type(8)));
typedef float    f32x4 __attribute__((ext_vector_type(4)));

#define MFMA16(a, b, c) __builtin_amdgcn_mfma_f32_16x16x32_f16((a), (b), (c), 0, 0, 0)

// ---------------------------------------------------------------------------
// LOCK-IN ROUND: verbatim resubmission of the round-3 kernel — the session's
// empirical best (argmin 63.7us, bench 143.9; MfmaUtil 33%, VGPR 64, no
// spill). Thirteen interventions against it were null or negative: ILP (R4),
// setprio (R4), barrier count (R5/R10), grain (R6), occupancy (R7-R9),
// manual reg-pipeline (R12), fused prep (R13), compiler reg-pipeline (R14),
// wave phase-stagger (R15). 33% MfmaUtil = the documented 2-phase
// LDS-staged structure plateau (m97/m233); the 8-phase escape needs a
// K-loop, and K=64 here is a single MFMA step.
//
// ws layout: csqr[1024] f32 (4 KB) | CBf: 16384 f16x8 units (256 KB)
// CBf unit index = tile*256 + f*64 + lane, f in {0:hi k0-31, 1:hi k32-63,
// 2:lo k0-31, 3:lo k32-63}; unit holds the 8 halves lane needs for that
// MFMA B fragment: B[k=(lane>>4)*8+j][n=lane&15], code = tile*16 + n.
// CBf stores the hi/lo split of (-2*c); dist = |c|^2 + x.(-2c).
// (Correctness-verified rounds 2-15.)
// ---------------------------------------------------------------------------
__global__ __launch_bounds__(256)
void prep_kernel(const float* __restrict__ CB, _Float16* __restrict__ CBf,
                 float* __restrict__ csqr, float* __restrict__ loss) {
    const int b = blockIdx.x, t = threadIdx.x;
    if (b < 64) {
        const int unit = b * 256 + t;
        const int tile = unit >> 8;
        const int f    = (unit >> 6) & 3;
        const int lane = unit & 63;
        const int quad = lane >> 4, lrow = lane & 15;
        const int code = tile * 16 + lrow;
        const int k0   = (f & 1) * 32 + quad * 8;
        const float* src = CB + (size_t)code * D + k0;
        float4 v0 = *(const float4*)(src);
        float4 v1 = *(const float4*)(src + 4);
        float xs[8] = {v0.x, v0.y, v0.z, v0.w, v1.x, v1.y, v1.z, v1.w};
        f16x8 o;
#pragma unroll
        for (int j = 0; j < 8; ++j) {
            float sv = -2.0f * xs[j];
            _Float16 h = (_Float16)sv;
            o[j] = (f < 2) ? h : (_Float16)(sv - (float)h);
        }
        *(f16x8*)(CBf + (size_t)unit * 8) = o;
    } else {
        if (t == 0) *loss = 0.0f;
        for (int k = t; k < K_CODES; k += 256) {
            const float4* p = (const float4*)(CB + (size_t)k * D);
            float s = 0.0f;
#pragma unroll
            for (int i = 0; i < 16; ++i) {
                float4 v = p[i];
                s += v.x * v.x + v.y * v.y + v.z * v.z + v.w * v.w;
            }
            csqr[k] = s;
        }
    }
}

// ---------------------------------------------------------------------------
// Direct global->LDS 16B copy (lane-linear dest: wave-uniform base + lane*16).
// ---------------------------------------------------------------------------
__device__ __forceinline__ void gload_lds16(const void* g, void* l) {
    __builtin_amdgcn_global_load_lds(
        (const __attribute__((address_space(1))) void*)g,
        (__attribute__((address_space(3))) void*)l,
        16, 0, 0);
}

// ---------------------------------------------------------------------------
// K1 (LDS-staged B, 2-barrier ring — the measured-best structure): block =
// 4 waves x 32 rows = 128 rows, each wave covers ALL 1024 codes. B tiles
// (4 KB = 16 codes of split(-2c) fragments) stream through a 2-buf x 4-tile
// LDS ring via global_load_lds dwordx4 (1 instr/thread/tile), consumed by
// all 4 waves. Counted s_waitcnt vmcnt(4) (never 0 in-loop) keeps the next
// group's 4 loads in flight across the raw s_barrier; sched_barrier(0)
// fences per rule #18. Per tile per wave: 4 ds_read_b128 + 12 MFMA
// (hh,hh,lh,lh,hl,hl; ll ~2^-24 dropped) + 8 cmp/cndmask argmin updates.
// Tie-break = global first-min: tiles ascend in-lane (strict <), 16-lane
// column reduce is index-lexicographic. LDS 37.4 KB -> 4 blocks/CU; grid
// 1024 = 4/CU. VGPR 64 under __launch_bounds__(256,4).
// Epilogue: per-wave idx/loss finalize, block-cooperative contiguous zq
// span write (16B-aligned despite out+1).
// ---------------------------------------------------------------------------
__global__ __launch_bounds__(256, 4)
void argmin_kernel(const float* __restrict__ X,
                   const _Float16* __restrict__ CBf,
                   const float* __restrict__ csqr,
                   const float* __restrict__ CB,
                   float* __restrict__ out) {
    __shared__ _Float16 Bring[2][4][2048];   // 2 bufs x 4 tiles x 4 KB
    __shared__ float LsC[K_CODES];           // csqr copy, 4 KB
    __shared__ int   ivfin[128];
    __shared__ float lsum[4];

    const int t    = threadIdx.x;
    const int wave = t >> 6;
    const int lane = t & 63;
    const int quad = lane >> 4;
    const int lrow = lane & 15;
    const int R0   = blockIdx.x * 128;
    const int Rw   = R0 + wave * 32;

// Stage group g (4 tiles) into buf: thread t loads unit tile*256+t (16 B)
// to LDS slot base + wave*1024 (+ lane*16 by hardware).
#define STAGE(g, buf)                                                         \
    do {                                                                      \
        _Pragma("unroll")                                                     \
        for (int i_ = 0; i_ < 4; ++i_) {                                      \
            const f16x8* gp_ =                                                \
                (const f16x8*)CBf + (size_t)((g) * 4 + i_) * 256 + t;         \
            gload_lds16((const void*)gp_,                                     \
                        (void*)((char*)&Bring[buf][i_][0] + (wave << 10)));   \
        }                                                                     \
    } while (0)

    STAGE(0, 0);                       // group 0 in flight ASAP

    // csqr -> LDS (covered by the barrier below).
    ((float4*)LsC)[t] = ((const float4*)csqr)[t];

    // ---- A fragments: split(x) hi/lo; per-wave xsq covers its 32 rows
    // exactly once (quads tile the 64 columns). Lane holds
    // A[m=lrow][k=quad*8+j] for rows Rw+mt*16+lrow.
    f16x8 Ah[2][2], Al[2][2];
    float xsq = 0.0f;
#pragma unroll
    for (int mt = 0; mt < 2; ++mt) {
        const float* xr = X + (size_t)(Rw + mt * 16 + lrow) * D;
#pragma unroll
        for (int ks = 0; ks < 2; ++ks) {
            const int k0 = ks * 32 + quad * 8;
            float4 v0 = *(const float4*)(xr + k0);
            float4 v1 = *(const float4*)(xr + k0 + 4);
            float xs[8] = {v0.x, v0.y, v0.z, v0.w, v1.x, v1.y, v1.z, v1.w};
            f16x8 h, l;
#pragma unroll
            for (int j = 0; j < 8; ++j) {
                xsq += xs[j] * xs[j];
                _Float16 hh = (_Float16)xs[j];
                h[j] = hh;
                l[j] = (_Float16)(xs[j] - (float)hh);
            }
            Ah[mt][ks] = h;
            Al[mt][ks] = l;
        }
    }
    __syncthreads();   // LsC + group 0 ready (full drain — prologue only)

    float bestd[2][4];
    int   besti[2][4];
#pragma unroll
    for (int mt = 0; mt < 2; ++mt)
#pragma unroll
        for (int r = 0; r < 4; ++r) { bestd[mt][r] = 3.0e38f; besti[mt][r] = 0; }

    // ---- Main loop: 16 groups x 4 tiles. Stage next group, counted-vmcnt
    // wait for current, barrier, consume, barrier (protects restage).
    for (int g = 0; g < 16; ++g) {
        if (g < 15) {
            STAGE(g + 1, (g + 1) & 1);
            asm volatile("s_waitcnt vmcnt(4)" ::: "memory");
        } else {
            asm volatile("s_waitcnt vmcnt(0)" ::: "memory");
        }
        __builtin_amdgcn_s_barrier();            // group g fully in LDS
        __builtin_amdgcn_sched_barrier(0);
        const _Float16* Bb = &Bring[g & 1][0][0];
#pragma unroll
        for (int i = 0; i < 4; ++i) {
            const f16x8* Bt = (const f16x8*)(Bb + i * 2048) + lane;
            f16x8 b0 = Bt[0], b1 = Bt[64], b2 = Bt[128], b3 = Bt[192];
            const int   c  = (g * 4 + i) * 16 + lrow;
            const float cs = LsC[c];
#pragma unroll
            for (int mt = 0; mt < 2; ++mt) {
                f32x4 acc = {cs, cs, cs, cs};
                acc = MFMA16(Ah[mt][0], b0, acc);
                acc = MFMA16(Ah[mt][1], b1, acc);
                acc = MFMA16(Al[mt][0], b0, acc);
                acc = MFMA16(Al[mt][1], b1, acc);
                acc = MFMA16(Ah[mt][0], b2, acc);
                acc = MFMA16(Ah[mt][1], b3, acc);
#pragma unroll
                for (int r = 0; r < 4; ++r) {
                    bool lt = acc[r] < bestd[mt][r];
                    bestd[mt][r] = lt ? acc[r] : bestd[mt][r];
                    besti[mt][r] = lt ? c : besti[mt][r];
                }
            }
        }
        __builtin_amdgcn_sched_barrier(0);       // pin reads/MFMAs here
        __builtin_amdgcn_s_barrier();            // all waves done with buf
    }

    // ---- Finalize: 16-lane column reduce (lexicographic on exact ties);
    // lrow==0 lanes hold rows Rw + mt*16 + quad*4 + r (C layout:
    // row = quad*4 + r, col = lrow — verified rounds 0-15).
    float dvsum = 0.0f;
#pragma unroll
    for (int mt = 0; mt < 2; ++mt) {
#pragma unroll
        for (int r = 0; r < 4; ++r) {
            float dv = bestd[mt][r];
            int   iv = besti[mt][r];
#pragma unroll
            for (int m = 1; m < 16; m <<= 1) {
                float od = __shfl_xor(dv, m, 64);
                int   oi = __shfl_xor(iv, m, 64);
                if (od < dv || (od == dv && oi < iv)) { dv = od; iv = oi; }
            }
            if (lrow == 0) {
                const int rl = wave * 32 + mt * 16 + quad * 4 + r;  // 0..127
                ivfin[rl] = iv;
                out[1 + (size_t)N_ROWS * D + R0 + rl] = (float)iv;  // idxf
                dvsum += dv;
            }
        }
    }

    // ---- Loss partial: xsq (all lanes) + dvsum (lrow==0 lanes) reduce.
    {
        float s = xsq + dvsum;
#pragma unroll
        for (int m = 1; m < 64; m <<= 1) s += __shfl_xor(s, m, 64);
        if (lane == 0) lsum[wave] = s;
    }
    __syncthreads();                             // ivfin + lsum ready

    const float scale = 1.25f / (float)((size_t)N_ROWS * D);
    if (t == 0)
        atomicAdd(out, (lsum[0] + lsum[1] + lsum[2] + lsum[3]) * scale);

    // ---- Block-cooperative zq span write: dwords [R0*64, R0*64+8192) at
    // out+1. Global dword offset 1+R0*64+j is 16B-aligned iff j%4==3.
    float* p = out + 1 + (size_t)R0 * D;
#pragma unroll
    for (int i = 0; i < 8; ++i) {
        int q = i * 256 + t;        // 0..2047
        int j = 4 * q + 3;          // 3,7,...,8191
        if (q < 2047) {
            float v[4];
#pragma unroll
            for (int e = 0; e < 4; ++e) {
                int jj = j + e;     // may straddle a row boundary
                v[e] = CB[(size_t)ivfin[jj >> 6] * D + (jj & 63)];
            }
            *(float4*)(p + j) = make_float4(v[0], v[1], v[2], v[3]);
        } else if (q == 2047) {
            p[8191] = CB[(size_t)ivfin[127] * D + 63];
        }
    }
    if (t == 0) {   // head dwords j=0..2 (row 0, cols 0..2)
        const float* c0 = CB + (size_t)ivfin[0] * D;
        p[0] = c0[0];
        p[1] = c0[1];
        p[2] = c0[2];
    }
}

// ---------------------------------------------------------------------------
extern "C" void kernel_launch(void* const* d_in, const int* in_sizes, int n_in,
                              void* d_out, int out_size, void* d_ws,
                              size_t ws_size, hipStream_t stream) {
    const float* X  = (const float*)d_in[0];   // inputs  [131072,64]
    const float* CB = (const float*)d_in[1];   // codebook [1024,64]

    float*    csqr = (float*)d_ws;                      // 4 KB
    _Float16* CBf  = (_Float16*)((char*)d_ws + 4096);   // 256 KB

    hipLaunchKernelGGL(prep_kernel, dim3(65), dim3(256), 0, stream,
                       CB, CBf, csqr, (float*)d_out);
    hipLaunchKernelGGL(argmin_kernel, dim3(N_ROWS / 128), dim3(256), 0, stream,
                       X, CBf, csqr, CB, (float*)d_out);
}